// Round 2
// baseline (321.405 us; speedup 1.0000x reference)
//
#include <hip/hip_runtime.h>
#include <hip/hip_bf16.h>

// Problem constants
#define NB    16          // batch
#define SP    1024        // H*W spatial
#define NC    512         // channels
#define NG    32          // groups
#define MTOT  (NB*SP)     // 16384
#define EPSV  1e-3f
#define SCALE 0.04419417382415922f  // 512^-0.5

using f32x4   = __attribute__((ext_vector_type(4))) float;
using short8  = __attribute__((ext_vector_type(8))) short;
using short4v = __attribute__((ext_vector_type(4))) short;
using bf16x8v = __attribute__((ext_vector_type(8))) __bf16;

__device__ __forceinline__ unsigned short f2bf(float f) {
  union { float f; unsigned int u; } x; x.f = f;
  unsigned int u = x.u;
  unsigned int r = (u + 0x7FFFu + ((u >> 16) & 1u)) >> 16;  // RNE
  return (unsigned short)r;
}

// ---------------------------------------------------------------- GN stats
__global__ __launch_bounds__(256) void gn_stats_k(const float* __restrict__ x,
                                                  float2* __restrict__ stats) {
  int bg = blockIdx.x;            // b*32+g
  int b = bg >> 5, g = bg & 31;
  int tid = threadIdx.x;
  int c = tid & 15, s0 = tid >> 4;
  const float* base = x + (long)b * SP * NC + g * 16 + c;
  float s = 0.f, ss = 0.f;
  for (int sp = s0; sp < SP; sp += 16) {
    float v = base[(long)sp * NC];
    s += v; ss += v * v;
  }
  for (int o = 32; o > 0; o >>= 1) { s += __shfl_xor(s, o); ss += __shfl_xor(ss, o); }
  __shared__ float rs[4], rss[4];
  int lane = tid & 63, wv = tid >> 6;
  if (lane == 0) { rs[wv] = s; rss[wv] = ss; }
  __syncthreads();
  if (tid == 0) {
    float S = rs[0] + rs[1] + rs[2] + rs[3];
    float SS = rss[0] + rss[1] + rss[2] + rss[3];
    float mean = S * (1.f / 16384.f);
    float var  = SS * (1.f / 16384.f) - mean * mean;
    stats[bg] = make_float2(mean, rsqrtf(var + EPSV));
  }
}

// ---------------------------------------------------------------- weight packing
// Wp[n=e*512+a][c] = W_qkv[c][a][e]   (bf16, n-major so GEMM B reads are linear)
__global__ __launch_bounds__(256) void pack_wqkv_k(const float* __restrict__ W,
                                                   const float* __restrict__ bq,
                                                   unsigned short* __restrict__ Wp,
                                                   float* __restrict__ bp) {
  int idx = blockIdx.x * 256 + threadIdx.x;     // 786432
  int n = idx >> 9, c = idx & 511;
  int e = n >> 9, a = n & 511;
  Wp[idx] = f2bf(W[((long)c * 512 + a) * 3 + e]);
  if (idx < 1536) {
    int e2 = idx >> 9, a2 = idx & 511;
    bp[idx] = bq[a2 * 3 + e2];
  }
}

// WoutT[d][c] = W_out[c][d]
__global__ __launch_bounds__(256) void pack_wout_k(const float* __restrict__ W,
                                                   unsigned short* __restrict__ Wp) {
  int idx = blockIdx.x * 256 + threadIdx.x;     // 262144
  int n = idx >> 9, c = idx & 511;
  Wp[idx] = f2bf(W[(long)c * 512 + n]);
}

// ---------------------------------------------------------------- V transpose
// vT[b][c][s] = qkv[b*1024+s][1024+c]
__global__ void transpose_v_k(const unsigned short* __restrict__ qkv,
                              unsigned short* __restrict__ vT) {
  __shared__ unsigned short t[32][33];
  int bs = blockIdx.x, bc = blockIdx.y, b = blockIdx.z;
  int tx = threadIdx.x, ty = threadIdx.y;     // 32 x 8
  #pragma unroll
  for (int k = 0; k < 4; ++k) {
    int s = bs * 32 + ty + k * 8, c = bc * 32 + tx;
    t[ty + k * 8][tx] = qkv[((long)b * SP + s) * 1536 + 1024 + c];
  }
  __syncthreads();
  #pragma unroll
  for (int k = 0; k < 4; ++k) {
    int c = bc * 32 + ty + k * 8, s = bs * 32 + tx;
    vT[((long)b * NC + c) * SP + s] = t[tx][ty + k * 8];
  }
}

// ---------------------------------------------------------------- softmax (in-place bf16 P over fp32 S)
__global__ __launch_bounds__(256) void softmax_k(float* __restrict__ S) {
  long row = blockIdx.x;
  const float* r = S + row * 1024;
  int tid = threadIdx.x, lane = tid & 63, wv = tid >> 6;
  f32x4 v = *reinterpret_cast<const f32x4*>(r + tid * 4);
  float m = fmaxf(fmaxf(v[0], v[1]), fmaxf(v[2], v[3]));
  for (int o = 32; o > 0; o >>= 1) m = fmaxf(m, __shfl_xor(m, o));
  __shared__ float wm[4], ws[4];
  if (lane == 0) wm[wv] = m;
  __syncthreads();
  float rmax = fmaxf(fmaxf(wm[0], wm[1]), fmaxf(wm[2], wm[3]));
  float e[4]; float ssum = 0.f;
  #pragma unroll
  for (int q = 0; q < 4; ++q) { e[q] = __expf(v[q] - rmax); ssum += e[q]; }
  for (int o = 32; o > 0; o >>= 1) ssum += __shfl_xor(ssum, o);
  if (lane == 0) ws[wv] = ssum;
  __syncthreads();
  float inv = 1.f / (ws[0] + ws[1] + ws[2] + ws[3]);
  short4v pv;
  #pragma unroll
  for (int q = 0; q < 4; ++q) pv[q] = (short)f2bf(e[q] * inv);
  // in-place: bf16 row occupies first half of the fp32 row's bytes; all reads done pre-sync
  unsigned short* P = reinterpret_cast<unsigned short*>(S);
  *reinterpret_cast<short4v*>(&P[row * 2048 + tid * 4]) = pv;
}

// ---------------------------------------------------------------- TN GEMM template
// C[m][n] = sum_k A[m][k] * B'[n][k]   (both LDS tiles fragment-major [row][k])
// AMODE: 0 = bf16 A, 1 = fp32 A with fused GroupNorm->bf16
// EPI:   0 = bf16 out + fp32 bias, 1 = fp32 out * scale, 2 = bf16 out, 3 = fp32 out + bias + residual
template <int AMODE, int EPI>
__global__ __launch_bounds__(256) void gemm_tn(
    const void* __restrict__ Apv, long strideA, int lda,
    const unsigned short* __restrict__ Bp, long strideB, int ldb,
    void* __restrict__ Op, long strideO, int ldo,
    const float* __restrict__ bias, const float* __restrict__ residual,
    const float2* __restrict__ stats,
    const float* __restrict__ gamma, const float* __restrict__ beta,
    int M, int N, int K, float scale) {
  __shared__ unsigned short As[128 * 72];
  __shared__ unsigned short Bs[128 * 72];
  const int tid = threadIdx.x;
  const int bm = blockIdx.y * 128, bn = blockIdx.x * 128;
  const int z = blockIdx.z;
  const int lane = tid & 63, wv = tid >> 6;
  const int wm = (wv >> 1) * 64, wn = (wv & 1) * 64;
  const int lrow = lane & 15, lk = (lane >> 4) * 8;
  const unsigned short* Bg = Bp + (long)z * strideB;

  f32x4 acc[4][4] = {};
  for (int kt = 0; kt < K; kt += 32) {
    // ---- stage B' tile [128 n][32 k]
    #pragma unroll
    for (int it = 0; it < 2; ++it) {
      int cch = tid + it * 256;
      int row = cch >> 2, k8 = (cch & 3) << 3;
      *reinterpret_cast<short8*>(&Bs[row * 72 + k8]) =
          *reinterpret_cast<const short8*>(Bg + (long)(bn + row) * ldb + kt + k8);
    }
    // ---- stage A tile [128 m][32 k]
    if (AMODE == 0) {
      const unsigned short* Ag = (const unsigned short*)Apv + (long)z * strideA;
      #pragma unroll
      for (int it = 0; it < 2; ++it) {
        int cch = tid + it * 256;
        int row = cch >> 2, k8 = (cch & 3) << 3;
        *reinterpret_cast<short8*>(&As[row * 72 + k8]) =
            *reinterpret_cast<const short8*>(Ag + (long)(bm + row) * lda + kt + k8);
      }
    } else {
      const float* Xg = (const float*)Apv + (long)z * strideA;
      #pragma unroll
      for (int it = 0; it < 4; ++it) {
        int cch = tid + it * 256;
        int row = cch >> 3, col = (cch & 7) << 2;
        int rg = bm + row, ch = kt + col;
        f32x4 v  = *reinterpret_cast<const f32x4*>(Xg + (long)rg * lda + ch);
        f32x4 gm = *reinterpret_cast<const f32x4*>(gamma + ch);
        f32x4 bt = *reinterpret_cast<const f32x4*>(beta + ch);
        float2 st = stats[(rg >> 10) * NG + (ch >> 4)];
        short4v pv;
        #pragma unroll
        for (int q = 0; q < 4; ++q) {
          float sc = st.y * gm[q];
          pv[q] = (short)f2bf(v[q] * sc + (bt[q] - st.x * sc));
        }
        *reinterpret_cast<short4v*>(&As[row * 72 + col]) = pv;
      }
    }
    __syncthreads();
    // ---- MFMA
    short8 afr[4], bfr[4];
    #pragma unroll
    for (int i = 0; i < 4; ++i)
      afr[i] = *reinterpret_cast<const short8*>(&As[(wm + i * 16 + lrow) * 72 + lk]);
    #pragma unroll
    for (int j = 0; j < 4; ++j)
      bfr[j] = *reinterpret_cast<const short8*>(&Bs[(wn + j * 16 + lrow) * 72 + lk]);
    #pragma unroll
    for (int i = 0; i < 4; ++i)
      #pragma unroll
      for (int j = 0; j < 4; ++j)
        acc[i][j] = __builtin_amdgcn_mfma_f32_16x16x32_bf16(
            __builtin_bit_cast(bf16x8v, afr[i]),
            __builtin_bit_cast(bf16x8v, bfr[j]), acc[i][j], 0, 0, 0);
    __syncthreads();
  }

  // ---- epilogue
  const int colb = bn + wn + (lane & 15);
  #pragma unroll
  for (int i = 0; i < 4; ++i) {
    #pragma unroll
    for (int r = 0; r < 4; ++r) {
      int rowg = bm + wm + i * 16 + (lane >> 4) * 4 + r;
      #pragma unroll
      for (int j = 0; j < 4; ++j) {
        int colg = colb + j * 16;
        float v = acc[i][j][r];
        if (EPI == 0) {
          v += bias[colg];
          ((unsigned short*)Op)[(long)z * strideO + (long)rowg * ldo + colg] = f2bf(v);
        } else if (EPI == 1) {
          ((float*)Op)[(long)z * strideO + (long)rowg * ldo + colg] = v * scale;
        } else if (EPI == 2) {
          ((unsigned short*)Op)[(long)z * strideO + (long)rowg * ldo + colg] = f2bf(v);
        } else {
          v += bias[colg] + residual[(long)rowg * ldo + colg];
          ((float*)Op)[(long)rowg * ldo + colg] = v;
        }
      }
    }
  }
}

// ---------------------------------------------------------------- launch
extern "C" void kernel_launch(void* const* d_in, const int* in_sizes, int n_in,
                              void* d_out, int out_size, void* d_ws, size_t ws_size,
                              hipStream_t stream) {
  const float* x     = (const float*)d_in[0];
  const float* gamma = (const float*)d_in[1];
  const float* beta  = (const float*)d_in[2];
  const float* Wqkv  = (const float*)d_in[3];
  const float* bqkv  = (const float*)d_in[4];
  const float* Wout  = (const float*)d_in[5];
  const float* bout  = (const float*)d_in[6];
  float* out = (float*)d_out;

  char* ws = (char*)d_ws;
  float2*         stats = (float2*)(ws + 0);                    //   4 KB
  unsigned short* wqkvP = (unsigned short*)(ws + 4096);         // 1.5 MB
  float*          bqP   = (float*)(ws + 1576960);               //   6 KB
  unsigned short* woutT = (unsigned short*)(ws + 1583104);      // 0.5 MB
  unsigned short* qkv   = (unsigned short*)(ws + 2107392);      //  48 MB  [16384][1536] bf16
  unsigned short* vT    = (unsigned short*)(ws + 52439040);     //  16 MB  [16][512][1024] bf16
  float*          Sbuf  = (float*)(ws + 69216256);              //  64 MB  [16][1024][1024] f32 (P bf16 in-place)
  unsigned short* attn  = (unsigned short*)(ws + 136325120);    //  16 MB  [16384][512] bf16

  gn_stats_k<<<512, 256, 0, stream>>>(x, stats);
  pack_wqkv_k<<<3072, 256, 0, stream>>>(Wqkv, bqkv, wqkvP, bqP);
  pack_wout_k<<<1024, 256, 0, stream>>>(Wout, woutT);

  // QKV projection with fused GroupNorm: [16384,512] x [1536,512]^T -> qkv bf16 [16384][1536]
  gemm_tn<1, 0><<<dim3(12, 128, 1), 256, 0, stream>>>(
      x, 0L, NC, wqkvP, 0L, NC, qkv, 0L, 1536,
      bqP, nullptr, stats, gamma, beta, MTOT, 1536, NC, 1.f);

  transpose_v_k<<<dim3(32, 16, 16), dim3(32, 8), 0, stream>>>(qkv, vT);

  // S = Q K^T * scale  (per batch): A=q (cols 0..511 of qkv), B'=k (cols 512..1023)
  gemm_tn<0, 1><<<dim3(8, 8, 16), 256, 0, stream>>>(
      qkv, (long)SP * 1536, 1536, qkv + 512, (long)SP * 1536, 1536,
      Sbuf, (long)SP * SP, SP, nullptr, nullptr, nullptr, nullptr, nullptr,
      SP, SP, NC, SCALE);

  softmax_k<<<MTOT, 256, 0, stream>>>(Sbuf);

  // attn_out = P V  (per batch): A=P bf16 (ld 2048 over reused S rows), B'=vT
  gemm_tn<0, 2><<<dim3(4, 8, 16), 256, 0, stream>>>(
      Sbuf, (long)SP * 2048, 2048, vT, (long)NC * SP, SP,
      attn, (long)SP * NC, NC, nullptr, nullptr, nullptr, nullptr, nullptr,
      SP, NC, SP, 1.f);

  // out = attn_out W_out + b_out + inputs
  gemm_tn<0, 3><<<dim3(4, 128, 1), 256, 0, stream>>>(
      attn, 0L, NC, woutT, 0L, NC, out, 0L, NC,
      bout, x, nullptr, nullptr, nullptr, MTOT, NC, NC, 1.f);
}

// Round 3
// 299.667 us; speedup vs baseline: 1.0725x; 1.0725x over previous
//
#include <hip/hip_runtime.h>
#include <hip/hip_bf16.h>

// Problem constants
#define NB    16          // batch
#define SP    1024        // H*W spatial
#define NC    512         // channels
#define NG    32          // groups
#define MTOT  (NB*SP)     // 16384
#define EPSV  1e-3f
#define SCALE 0.04419417382415922f  // 512^-0.5

using f32x4   = __attribute__((ext_vector_type(4))) float;
using short8  = __attribute__((ext_vector_type(8))) short;
using short4v = __attribute__((ext_vector_type(4))) short;
using bf16x8v = __attribute__((ext_vector_type(8))) __bf16;

__device__ __forceinline__ unsigned short f2bf(float f) {
  union { float f; unsigned int u; } x; x.f = f;
  unsigned int u = x.u;
  unsigned int r = (u + 0x7FFFu + ((u >> 16) & 1u)) >> 16;  // RNE
  return (unsigned short)r;
}

// async 16B global->LDS (gfx950). LDS dest = wave-uniform base + lane*16.
#define GLOAD_LDS16(g, l)                                                     \
  __builtin_amdgcn_global_load_lds(                                           \
      (const __attribute__((address_space(1))) void*)(g),                     \
      (__attribute__((address_space(3))) void*)(l), 16, 0, 0)

// ---------------------------------------------------------------- GN stats
__global__ __launch_bounds__(256) void gn_stats_k(const float* __restrict__ x,
                                                  float2* __restrict__ stats) {
  int bg = blockIdx.x;            // b*32+g
  int b = bg >> 5, g = bg & 31;
  int tid = threadIdx.x;
  int c = tid & 15, s0 = tid >> 4;
  const float* base = x + (long)b * SP * NC + g * 16 + c;
  float s = 0.f, ss = 0.f;
  for (int sp = s0; sp < SP; sp += 16) {
    float v = base[(long)sp * NC];
    s += v; ss += v * v;
  }
  for (int o = 32; o > 0; o >>= 1) { s += __shfl_xor(s, o); ss += __shfl_xor(ss, o); }
  __shared__ float rs[4], rss[4];
  int lane = tid & 63, wv = tid >> 6;
  if (lane == 0) { rs[wv] = s; rss[wv] = ss; }
  __syncthreads();
  if (tid == 0) {
    float S = rs[0] + rs[1] + rs[2] + rs[3];
    float SS = rss[0] + rss[1] + rss[2] + rss[3];
    float mean = S * (1.f / 16384.f);
    float var  = SS * (1.f / 16384.f) - mean * mean;
    stats[bg] = make_float2(mean, rsqrtf(var + EPSV));
  }
}

// ---------------------------------------------------------------- GN apply -> xn bf16
__global__ __launch_bounds__(256) void gn_apply_k(const float* __restrict__ x,
                                                  const float2* __restrict__ stats,
                                                  const float* __restrict__ gamma,
                                                  const float* __restrict__ beta,
                                                  unsigned short* __restrict__ xn) {
  long t = (long)blockIdx.x * 256 + threadIdx.x;   // 1,048,576 threads, 8 elems each
  long base = t * 8;
  int c = (int)(base & 511);
  int b = (int)(base >> 19);                        // base / (512*1024)
  float2 st = stats[b * NG + (c >> 4)];
  f32x4 v0 = *reinterpret_cast<const f32x4*>(x + base);
  f32x4 v1 = *reinterpret_cast<const f32x4*>(x + base + 4);
  f32x4 g0 = *reinterpret_cast<const f32x4*>(gamma + c);
  f32x4 g1 = *reinterpret_cast<const f32x4*>(gamma + c + 4);
  f32x4 b0 = *reinterpret_cast<const f32x4*>(beta + c);
  f32x4 b1 = *reinterpret_cast<const f32x4*>(beta + c + 4);
  short8 o;
  #pragma unroll
  for (int q = 0; q < 4; ++q) {
    float sc = st.y * g0[q];
    o[q] = (short)f2bf(v0[q] * sc + (b0[q] - st.x * sc));
  }
  #pragma unroll
  for (int q = 0; q < 4; ++q) {
    float sc = st.y * g1[q];
    o[q + 4] = (short)f2bf(v1[q] * sc + (b1[q] - st.x * sc));
  }
  *reinterpret_cast<short8*>(xn + base) = o;
}

// ---------------------------------------------------------------- weight packing
// Wp[n=e*512+a][c] = W_qkv[c][a][e]   (bf16, n-major so GEMM B reads are linear)
__global__ __launch_bounds__(256) void pack_wqkv_k(const float* __restrict__ W,
                                                   const float* __restrict__ bq,
                                                   unsigned short* __restrict__ Wp,
                                                   float* __restrict__ bp) {
  int idx = blockIdx.x * 256 + threadIdx.x;     // 786432
  int n = idx >> 9, c = idx & 511;
  int e = n >> 9, a = n & 511;
  Wp[idx] = f2bf(W[((long)c * 512 + a) * 3 + e]);
  if (idx < 1536) {
    int e2 = idx >> 9, a2 = idx & 511;
    bp[idx] = bq[a2 * 3 + e2];
  }
}

// WoutT[d][c] = W_out[c][d]
__global__ __launch_bounds__(256) void pack_wout_k(const float* __restrict__ W,
                                                   unsigned short* __restrict__ Wp) {
  int idx = blockIdx.x * 256 + threadIdx.x;     // 262144
  int n = idx >> 9, c = idx & 511;
  Wp[idx] = f2bf(W[(long)c * 512 + n]);
}

// ---------------------------------------------------------------- V transpose
// vT[b][c][s] = qkv[b*1024+s][1024+c]
__global__ void transpose_v_k(const unsigned short* __restrict__ qkv,
                              unsigned short* __restrict__ vT) {
  __shared__ unsigned short t[32][33];
  int bs = blockIdx.x, bc = blockIdx.y, b = blockIdx.z;
  int tx = threadIdx.x, ty = threadIdx.y;     // 32 x 8
  #pragma unroll
  for (int k = 0; k < 4; ++k) {
    int s = bs * 32 + ty + k * 8, c = bc * 32 + tx;
    t[ty + k * 8][tx] = qkv[((long)b * SP + s) * 1536 + 1024 + c];
  }
  __syncthreads();
  #pragma unroll
  for (int k = 0; k < 4; ++k) {
    int c = bc * 32 + ty + k * 8, s = bs * 32 + tx;
    vT[((long)b * NC + c) * SP + s] = t[tx][ty + k * 8];
  }
}

// ---------------------------------------------------------------- softmax (in-place bf16 P over fp32 S)
__global__ __launch_bounds__(256) void softmax_k(float* __restrict__ S) {
  long row = blockIdx.x;
  const float* r = S + row * 1024;
  int tid = threadIdx.x, lane = tid & 63, wv = tid >> 6;
  f32x4 v = *reinterpret_cast<const f32x4*>(r + tid * 4);
  float m = fmaxf(fmaxf(v[0], v[1]), fmaxf(v[2], v[3]));
  for (int o = 32; o > 0; o >>= 1) m = fmaxf(m, __shfl_xor(m, o));
  __shared__ float wm[4], ws[4];
  if (lane == 0) wm[wv] = m;
  __syncthreads();
  float rmax = fmaxf(fmaxf(wm[0], wm[1]), fmaxf(wm[2], wm[3]));
  float e[4]; float ssum = 0.f;
  #pragma unroll
  for (int q = 0; q < 4; ++q) { e[q] = __expf(v[q] - rmax); ssum += e[q]; }
  for (int o = 32; o > 0; o >>= 1) ssum += __shfl_xor(ssum, o);
  if (lane == 0) ws[wv] = ssum;
  __syncthreads();
  float inv = 1.f / (ws[0] + ws[1] + ws[2] + ws[3]);
  short4v pv;
  #pragma unroll
  for (int q = 0; q < 4; ++q) pv[q] = (short)f2bf(e[q] * inv);
  // in-place: bf16 row occupies first half of the fp32 row's bytes; all reads done pre-sync
  unsigned short* P = reinterpret_cast<unsigned short*>(S);
  *reinterpret_cast<short4v*>(&P[row * 2048 + tid * 4]) = pv;
}

// ---------------------------------------------------------------- TN GEMM (m97 structure)
// C[m][n] = sum_k A[m][k] * B'[n][k], both bf16, global_load_lds staging,
// linear LDS [128][32] (NO padding - gload_lds needs contiguous dest).
// EPI: 0 = bf16 out + fp32 bias, 1 = fp32 out * scale, 2 = bf16 out,
//      3 = fp32 out + bias + residual
template <int EPI>
__global__ __launch_bounds__(256) void gemm_tn(
    const unsigned short* __restrict__ Ap, long strideA, int lda,
    const unsigned short* __restrict__ Bp, long strideB, int ldb,
    void* __restrict__ Op, long strideO, int ldo,
    const float* __restrict__ bias, const float* __restrict__ residual,
    int K, float scale) {
  __shared__ unsigned short As[128 * 32];
  __shared__ unsigned short Bs[128 * 32];
  const int tid = threadIdx.x;
  const int lane = tid & 63, wv = tid >> 6;
  const int bm = blockIdx.y * 128, bn = blockIdx.x * 128;
  const int z = blockIdx.z;
  const unsigned short* Ag = Ap + (long)z * strideA;
  const unsigned short* Bg = Bp + (long)z * strideB;

  const int srow = lane >> 2;          // 0..15 row within 16-row chunk
  const int scol = (lane & 3) * 8;     // element col 0,8,16,24
  const int wm = (wv >> 1) * 64, wn = (wv & 1) * 64;
  const int lrow = lane & 15, lk = (lane >> 4) * 8;

  f32x4 acc[4][4] = {};
  for (int kt = 0; kt < K; kt += 32) {
    #pragma unroll
    for (int it = 0; it < 2; ++it) {
      int chunk = it * 4 + wv;               // 0..7 (wave-uniform)
      int row = chunk * 16 + srow;
      GLOAD_LDS16(Ag + (long)(bm + row) * lda + kt + scol, As + chunk * 512);
      GLOAD_LDS16(Bg + (long)(bn + row) * ldb + kt + scol, Bs + chunk * 512);
    }
    __syncthreads();   // drains vmcnt(0): LDS tiles complete

    short8 afr[4], bfr[4];
    #pragma unroll
    for (int i = 0; i < 4; ++i)
      afr[i] = *reinterpret_cast<const short8*>(&As[(wm + i * 16 + lrow) * 32 + lk]);
    #pragma unroll
    for (int j = 0; j < 4; ++j)
      bfr[j] = *reinterpret_cast<const short8*>(&Bs[(wn + j * 16 + lrow) * 32 + lk]);
    #pragma unroll
    for (int i = 0; i < 4; ++i)
      #pragma unroll
      for (int j = 0; j < 4; ++j)
        acc[i][j] = __builtin_amdgcn_mfma_f32_16x16x32_bf16(
            __builtin_bit_cast(bf16x8v, afr[i]),
            __builtin_bit_cast(bf16x8v, bfr[j]), acc[i][j], 0, 0, 0);
    __syncthreads();
  }

  // ---- epilogue  (C/D map: col=lane&15, row=(lane>>4)*4+reg  [m89])
  const int colb = bn + wn + (lane & 15);
  #pragma unroll
  for (int i = 0; i < 4; ++i) {
    #pragma unroll
    for (int r = 0; r < 4; ++r) {
      int rowg = bm + wm + i * 16 + (lane >> 4) * 4 + r;
      #pragma unroll
      for (int j = 0; j < 4; ++j) {
        int colg = colb + j * 16;
        float v = acc[i][j][r];
        if (EPI == 0) {
          v += bias[colg];
          ((unsigned short*)Op)[(long)z * strideO + (long)rowg * ldo + colg] = f2bf(v);
        } else if (EPI == 1) {
          ((float*)Op)[(long)z * strideO + (long)rowg * ldo + colg] = v * scale;
        } else if (EPI == 2) {
          ((unsigned short*)Op)[(long)z * strideO + (long)rowg * ldo + colg] = f2bf(v);
        } else {
          v += bias[colg] + residual[(long)rowg * ldo + colg];
          ((float*)Op)[(long)rowg * ldo + colg] = v;
        }
      }
    }
  }
}

// ---------------------------------------------------------------- launch
extern "C" void kernel_launch(void* const* d_in, const int* in_sizes, int n_in,
                              void* d_out, int out_size, void* d_ws, size_t ws_size,
                              hipStream_t stream) {
  const float* x     = (const float*)d_in[0];
  const float* gamma = (const float*)d_in[1];
  const float* beta  = (const float*)d_in[2];
  const float* Wqkv  = (const float*)d_in[3];
  const float* bqkv  = (const float*)d_in[4];
  const float* Wout  = (const float*)d_in[5];
  const float* bout  = (const float*)d_in[6];
  float* out = (float*)d_out;

  char* ws = (char*)d_ws;
  float2*         stats = (float2*)(ws + 0);                    //   4 KB
  unsigned short* wqkvP = (unsigned short*)(ws + 4096);         // 1.5 MB
  float*          bqP   = (float*)(ws + 1576960);               //   6 KB
  unsigned short* woutT = (unsigned short*)(ws + 1583104);      // 0.5 MB
  unsigned short* qkv   = (unsigned short*)(ws + 2107392);      //  48 MB  [16384][1536] bf16
  unsigned short* vT    = (unsigned short*)(ws + 52439040);     //  16 MB  [16][512][1024] bf16
  float*          Sbuf  = (float*)(ws + 69216256);              //  64 MB  [16][1024][1024] f32 (P bf16 in-place)
  unsigned short* attn  = (unsigned short*)(ws + 136325120);    //  16 MB  [16384][512] bf16
  unsigned short* xn    = (unsigned short*)(ws + 153102336);    //  16 MB  [16384][512] bf16

  gn_stats_k<<<512, 256, 0, stream>>>(x, stats);
  gn_apply_k<<<4096, 256, 0, stream>>>(x, stats, gamma, beta, xn);
  pack_wqkv_k<<<3072, 256, 0, stream>>>(Wqkv, bqkv, wqkvP, bqP);
  pack_wout_k<<<1024, 256, 0, stream>>>(Wout, woutT);

  // QKV projection: xn [16384,512] x wqkvP [1536,512]^T -> qkv bf16 [16384][1536]
  gemm_tn<0><<<dim3(12, 128, 1), 256, 0, stream>>>(
      xn, 0L, NC, wqkvP, 0L, NC, qkv, 0L, 1536,
      bqP, nullptr, NC, 1.f);

  transpose_v_k<<<dim3(32, 16, 16), dim3(32, 8), 0, stream>>>(qkv, vT);

  // S = Q K^T * scale  (per batch): A=q (cols 0..511 of qkv), B'=k (cols 512..1023)
  gemm_tn<1><<<dim3(8, 8, 16), 256, 0, stream>>>(
      qkv, (long)SP * 1536, 1536, qkv + 512, (long)SP * 1536, 1536,
      Sbuf, (long)SP * SP, SP, nullptr, nullptr, NC, SCALE);

  softmax_k<<<MTOT, 256, 0, stream>>>(Sbuf);

  // attn_out = P V  (per batch): A=P bf16 (ld 2048 over reused S rows), B'=vT
  gemm_tn<2><<<dim3(4, 8, 16), 256, 0, stream>>>(
      (const unsigned short*)Sbuf, (long)SP * 2048, 2048, vT, (long)NC * SP, SP,
      attn, (long)SP * NC, NC, nullptr, nullptr, SP, 1.f);

  // out = attn_out W_out + b_out + inputs
  gemm_tn<3><<<dim3(4, 128, 1), 256, 0, stream>>>(
      attn, 0L, NC, woutT, 0L, NC, out, 0L, NC,
      bout, x, NC, 1.f);
}

// Round 4
// 291.822 us; speedup vs baseline: 1.1014x; 1.0269x over previous
//
#include <hip/hip_runtime.h>
#include <hip/hip_bf16.h>

// Problem constants
#define NB    16          // batch
#define SP    1024        // H*W spatial
#define NC    512         // channels
#define NG    32          // groups
#define MTOT  (NB*SP)     // 16384
#define EPSV  1e-3f
#define SCALE 0.04419417382415922f  // 512^-0.5

using f32x4   = __attribute__((ext_vector_type(4))) float;
using short8  = __attribute__((ext_vector_type(8))) short;
using short4v = __attribute__((ext_vector_type(4))) short;
using bf16x8v = __attribute__((ext_vector_type(8))) __bf16;

__device__ __forceinline__ unsigned short f2bf(float f) {
  union { float f; unsigned int u; } x; x.f = f;
  unsigned int u = x.u;
  unsigned int r = (u + 0x7FFFu + ((u >> 16) & 1u)) >> 16;  // RNE
  return (unsigned short)r;
}
__device__ __forceinline__ float bf2f(unsigned short b) {
  union { unsigned int u; float f; } x; x.u = ((unsigned int)b) << 16;
  return x.f;
}

// async 16B global->LDS (gfx950). LDS dest = wave-uniform base + lane*16.
#define GLOAD_LDS16(g, l)                                                     \
  __builtin_amdgcn_global_load_lds(                                           \
      (const __attribute__((address_space(1))) void*)(g),                     \
      (__attribute__((address_space(3))) void*)(l), 16, 0, 0)

// ---------------------------------------------------------------- GN stats
__global__ __launch_bounds__(256) void gn_stats_k(const float* __restrict__ x,
                                                  float2* __restrict__ stats) {
  int bg = blockIdx.x;            // b*32+g
  int b = bg >> 5, g = bg & 31;
  int tid = threadIdx.x;
  int c = tid & 15, s0 = tid >> 4;
  const float* base = x + (long)b * SP * NC + g * 16 + c;
  float s = 0.f, ss = 0.f;
  for (int sp = s0; sp < SP; sp += 16) {
    float v = base[(long)sp * NC];
    s += v; ss += v * v;
  }
  for (int o = 32; o > 0; o >>= 1) { s += __shfl_xor(s, o); ss += __shfl_xor(ss, o); }
  __shared__ float rs[4], rss[4];
  int lane = tid & 63, wv = tid >> 6;
  if (lane == 0) { rs[wv] = s; rss[wv] = ss; }
  __syncthreads();
  if (tid == 0) {
    float S = rs[0] + rs[1] + rs[2] + rs[3];
    float SS = rss[0] + rss[1] + rss[2] + rss[3];
    float mean = S * (1.f / 16384.f);
    float var  = SS * (1.f / 16384.f) - mean * mean;
    stats[bg] = make_float2(mean, rsqrtf(var + EPSV));
  }
}

// ---------------------------------------------------------------- GN apply -> xn bf16
__global__ __launch_bounds__(256) void gn_apply_k(const float* __restrict__ x,
                                                  const float2* __restrict__ stats,
                                                  const float* __restrict__ gamma,
                                                  const float* __restrict__ beta,
                                                  unsigned short* __restrict__ xn) {
  long t = (long)blockIdx.x * 256 + threadIdx.x;   // 1,048,576 threads, 8 elems each
  long base = t * 8;
  int c = (int)(base & 511);
  int b = (int)(base >> 19);                        // base / (512*1024)
  float2 st = stats[b * NG + (c >> 4)];
  f32x4 v0 = *reinterpret_cast<const f32x4*>(x + base);
  f32x4 v1 = *reinterpret_cast<const f32x4*>(x + base + 4);
  f32x4 g0 = *reinterpret_cast<const f32x4*>(gamma + c);
  f32x4 g1 = *reinterpret_cast<const f32x4*>(gamma + c + 4);
  f32x4 b0 = *reinterpret_cast<const f32x4*>(beta + c);
  f32x4 b1 = *reinterpret_cast<const f32x4*>(beta + c + 4);
  short8 o;
  #pragma unroll
  for (int q = 0; q < 4; ++q) {
    float sc = st.y * g0[q];
    o[q] = (short)f2bf(v0[q] * sc + (b0[q] - st.x * sc));
  }
  #pragma unroll
  for (int q = 0; q < 4; ++q) {
    float sc = st.y * g1[q];
    o[q + 4] = (short)f2bf(v1[q] * sc + (b1[q] - st.x * sc));
  }
  *reinterpret_cast<short8*>(xn + base) = o;
}

// ---------------------------------------------------------------- weight packing
// Wp[n=e*512+a][c] = W_qkv[c][a][e]   (bf16, n-major so GEMM B reads are linear)
__global__ __launch_bounds__(256) void pack_wqkv_k(const float* __restrict__ W,
                                                   const float* __restrict__ bq,
                                                   unsigned short* __restrict__ Wp,
                                                   float* __restrict__ bp) {
  int idx = blockIdx.x * 256 + threadIdx.x;     // 786432
  int n = idx >> 9, c = idx & 511;
  int e = n >> 9, a = n & 511;
  Wp[idx] = f2bf(W[((long)c * 512 + a) * 3 + e]);
  if (idx < 1536) {
    int e2 = idx >> 9, a2 = idx & 511;
    bp[idx] = bq[a2 * 3 + e2];
  }
}

// WoutT[d][c] = W_out[c][d]
__global__ __launch_bounds__(256) void pack_wout_k(const float* __restrict__ W,
                                                   unsigned short* __restrict__ Wp) {
  int idx = blockIdx.x * 256 + threadIdx.x;     // 262144
  int n = idx >> 9, c = idx & 511;
  Wp[idx] = f2bf(W[(long)c * 512 + n]);
}

// ---------------------------------------------------------------- V transpose
// vT[b][c][s] = qkv[b*1024+s][1024+c]
__global__ void transpose_v_k(const unsigned short* __restrict__ qkv,
                              unsigned short* __restrict__ vT) {
  __shared__ unsigned short t[32][33];
  int bs = blockIdx.x, bc = blockIdx.y, b = blockIdx.z;
  int tx = threadIdx.x, ty = threadIdx.y;     // 32 x 8
  #pragma unroll
  for (int k = 0; k < 4; ++k) {
    int s = bs * 32 + ty + k * 8, c = bc * 32 + tx;
    t[ty + k * 8][tx] = qkv[((long)b * SP + s) * 1536 + 1024 + c];
  }
  __syncthreads();
  #pragma unroll
  for (int k = 0; k < 4; ++k) {
    int c = bc * 32 + ty + k * 8, s = bs * 32 + tx;
    vT[((long)b * NC + c) * SP + s] = t[tx][ty + k * 8];
  }
}

// ---------------------------------------------------------------- softmax (bf16 in-place)
__global__ __launch_bounds__(256) void softmax_k(unsigned short* __restrict__ S) {
  long row = blockIdx.x;
  unsigned short* r = S + row * 1024;
  int tid = threadIdx.x, lane = tid & 63, wv = tid >> 6;
  short4v raw = *reinterpret_cast<const short4v*>(r + tid * 4);
  float v[4];
  #pragma unroll
  for (int q = 0; q < 4; ++q) v[q] = bf2f((unsigned short)raw[q]);
  float m = fmaxf(fmaxf(v[0], v[1]), fmaxf(v[2], v[3]));
  for (int o = 32; o > 0; o >>= 1) m = fmaxf(m, __shfl_xor(m, o));
  __shared__ float wm[4], ws[4];
  if (lane == 0) wm[wv] = m;
  __syncthreads();
  float rmax = fmaxf(fmaxf(wm[0], wm[1]), fmaxf(wm[2], wm[3]));
  float e[4]; float ssum = 0.f;
  #pragma unroll
  for (int q = 0; q < 4; ++q) { e[q] = __expf(v[q] - rmax); ssum += e[q]; }
  for (int o = 32; o > 0; o >>= 1) ssum += __shfl_xor(ssum, o);
  if (lane == 0) ws[wv] = ssum;
  __syncthreads();
  float inv = 1.f / (ws[0] + ws[1] + ws[2] + ws[3]);
  short4v pv;
  #pragma unroll
  for (int q = 0; q < 4; ++q) pv[q] = (short)f2bf(e[q] * inv);
  *reinterpret_cast<short4v*>(r + tid * 4) = pv;
}

// ---------------------------------------------------------------- TN GEMM (m97 structure + XCD swizzle)
// C[m][n] = sum_k A[m][k] * B'[n][k], both bf16, global_load_lds staging,
// linear LDS [128][32].  Requires gridDim.x*gridDim.y % 8 == 0.
// EPI: 0 = bf16 out + fp32 bias, 2 = bf16 out * scale,
//      3 = fp32 out + bias + residual
template <int EPI>
__global__ __launch_bounds__(256) void gemm_tn(
    const unsigned short* __restrict__ Ap, long strideA, int lda,
    const unsigned short* __restrict__ Bp, long strideB, int ldb,
    void* __restrict__ Op, long strideO, int ldo,
    const float* __restrict__ bias, const float* __restrict__ residual,
    int K, float scale) {
  __shared__ unsigned short As[128 * 32];
  __shared__ unsigned short Bs[128 * 32];
  const int tid = threadIdx.x;
  const int lane = tid & 63, wv = tid >> 6;

  // ---- bijective XCD swizzle (m204): each XCD gets a contiguous y-major chunk
  const int nwg  = gridDim.x * gridDim.y;
  const int flat = blockIdx.y * gridDim.x + blockIdx.x;  // hw-linear id within z-plane
  const int w    = (flat & 7) * (nwg >> 3) + (flat >> 3);
  const int bn = (w % gridDim.x) * 128;
  const int bm = (w / gridDim.x) * 128;
  const int z = blockIdx.z;
  const unsigned short* Ag = Ap + (long)z * strideA;
  const unsigned short* Bg = Bp + (long)z * strideB;

  const int srow = lane >> 2;          // 0..15 row within 16-row chunk
  const int scol = (lane & 3) * 8;     // element col 0,8,16,24
  const int wm = (wv >> 1) * 64, wn = (wv & 1) * 64;
  const int lrow = lane & 15, lk = (lane >> 4) * 8;

  f32x4 acc[4][4] = {};
  for (int kt = 0; kt < K; kt += 32) {
    #pragma unroll
    for (int it = 0; it < 2; ++it) {
      int chunk = it * 4 + wv;               // 0..7 (wave-uniform)
      int row = chunk * 16 + srow;
      GLOAD_LDS16(Ag + (long)(bm + row) * lda + kt + scol, As + chunk * 512);
      GLOAD_LDS16(Bg + (long)(bn + row) * ldb + kt + scol, Bs + chunk * 512);
    }
    __syncthreads();   // drains vmcnt(0): LDS tiles complete

    short8 afr[4], bfr[4];
    #pragma unroll
    for (int i = 0; i < 4; ++i)
      afr[i] = *reinterpret_cast<const short8*>(&As[(wm + i * 16 + lrow) * 32 + lk]);
    #pragma unroll
    for (int j = 0; j < 4; ++j)
      bfr[j] = *reinterpret_cast<const short8*>(&Bs[(wn + j * 16 + lrow) * 32 + lk]);
    #pragma unroll
    for (int i = 0; i < 4; ++i)
      #pragma unroll
      for (int j = 0; j < 4; ++j)
        acc[i][j] = __builtin_amdgcn_mfma_f32_16x16x32_bf16(
            __builtin_bit_cast(bf16x8v, afr[i]),
            __builtin_bit_cast(bf16x8v, bfr[j]), acc[i][j], 0, 0, 0);
    __syncthreads();
  }

  // ---- epilogue  (C/D map: col=lane&15, row=(lane>>4)*4+reg  [m89])
  const int colb = bn + wn + (lane & 15);
  #pragma unroll
  for (int i = 0; i < 4; ++i) {
    #pragma unroll
    for (int r = 0; r < 4; ++r) {
      int rowg = bm + wm + i * 16 + (lane >> 4) * 4 + r;
      #pragma unroll
      for (int j = 0; j < 4; ++j) {
        int colg = colb + j * 16;
        float v = acc[i][j][r];
        if (EPI == 0) {
          v += bias[colg];
          ((unsigned short*)Op)[(long)z * strideO + (long)rowg * ldo + colg] = f2bf(v);
        } else if (EPI == 2) {
          ((unsigned short*)Op)[(long)z * strideO + (long)rowg * ldo + colg] = f2bf(v * scale);
        } else {
          v += bias[colg] + residual[(long)rowg * ldo + colg];
          ((float*)Op)[(long)rowg * ldo + colg] = v;
        }
      }
    }
  }
}

// ---------------------------------------------------------------- launch
extern "C" void kernel_launch(void* const* d_in, const int* in_sizes, int n_in,
                              void* d_out, int out_size, void* d_ws, size_t ws_size,
                              hipStream_t stream) {
  const float* x     = (const float*)d_in[0];
  const float* gamma = (const float*)d_in[1];
  const float* beta  = (const float*)d_in[2];
  const float* Wqkv  = (const float*)d_in[3];
  const float* bqkv  = (const float*)d_in[4];
  const float* Wout  = (const float*)d_in[5];
  const float* bout  = (const float*)d_in[6];
  float* out = (float*)d_out;

  char* ws = (char*)d_ws;
  float2*         stats = (float2*)(ws + 0);                    //   4 KB
  unsigned short* wqkvP = (unsigned short*)(ws + 4096);         // 1.5 MB
  float*          bqP   = (float*)(ws + 1576960);               //   6 KB
  unsigned short* woutT = (unsigned short*)(ws + 1583104);      // 0.5 MB
  unsigned short* qkv   = (unsigned short*)(ws + 2107392);      //  48 MB  [16384][1536] bf16
  unsigned short* vT    = (unsigned short*)(ws + 52439040);     //  16 MB  [16][512][1024] bf16
  unsigned short* Sbuf  = (unsigned short*)(ws + 69216256);     //  32 MB  [16][1024][1024] bf16 (P in-place)
  unsigned short* attn  = (unsigned short*)(ws + 136325120);    //  16 MB  [16384][512] bf16
  unsigned short* xn    = (unsigned short*)(ws + 153102336);    //  16 MB  [16384][512] bf16

  gn_stats_k<<<512, 256, 0, stream>>>(x, stats);
  gn_apply_k<<<4096, 256, 0, stream>>>(x, stats, gamma, beta, xn);
  pack_wqkv_k<<<3072, 256, 0, stream>>>(Wqkv, bqkv, wqkvP, bqP);
  pack_wout_k<<<1024, 256, 0, stream>>>(Wout, woutT);

  // QKV projection: xn [16384,512] x wqkvP [1536,512]^T -> qkv bf16 [16384][1536]
  gemm_tn<0><<<dim3(12, 128, 1), 256, 0, stream>>>(
      xn, 0L, NC, wqkvP, 0L, NC, qkv, 0L, 1536,
      bqP, nullptr, NC, 1.f);

  transpose_v_k<<<dim3(32, 16, 16), dim3(32, 8), 0, stream>>>(qkv, vT);

  // S = Q K^T * scale (bf16 out, per batch): A=q (cols 0..511), B'=k (cols 512..1023)
  gemm_tn<2><<<dim3(8, 8, 16), 256, 0, stream>>>(
      qkv, (long)SP * 1536, 1536, qkv + 512, (long)SP * 1536, 1536,
      Sbuf, (long)SP * SP, SP, nullptr, nullptr, NC, SCALE);

  softmax_k<<<MTOT, 256, 0, stream>>>(Sbuf);

  // attn_out = P V  (per batch): A=P bf16 [1024][1024], B'=vT
  gemm_tn<2><<<dim3(4, 8, 16), 256, 0, stream>>>(
      Sbuf, (long)SP * SP, SP, vT, (long)NC * SP, SP,
      attn, (long)SP * NC, NC, nullptr, nullptr, SP, 1.f);

  // out = attn_out W_out + b_out + inputs
  gemm_tn<3><<<dim3(4, 128, 1), 256, 0, stream>>>(
      attn, 0L, NC, woutT, 0L, NC, out, 0L, NC,
      bout, x, NC, 1.f);
}

// Round 8
// 279.593 us; speedup vs baseline: 1.1495x; 1.0437x over previous
//
#include <hip/hip_runtime.h>
#include <hip/hip_bf16.h>

// Problem constants
#define NB    16          // batch
#define SP    1024        // H*W spatial
#define NC    512         // channels
#define NG    32          // groups
#define MTOT  (NB*SP)     // 16384
#define EPSV  1e-3f
#define SCALE 0.04419417382415922f  // 512^-0.5

using f32x4   = __attribute__((ext_vector_type(4))) float;
using short8  = __attribute__((ext_vector_type(8))) short;
using short4v = __attribute__((ext_vector_type(4))) short;
using bf16x8v = __attribute__((ext_vector_type(8))) __bf16;

__device__ __forceinline__ unsigned short f2bf(float f) {
  union { float f; unsigned int u; } x; x.f = f;
  unsigned int u = x.u;
  unsigned int r = (u + 0x7FFFu + ((u >> 16) & 1u)) >> 16;  // RNE
  return (unsigned short)r;
}
__device__ __forceinline__ float bf2f(unsigned short b) {
  union { unsigned int u; float f; } x; x.u = ((unsigned int)b) << 16;
  return x.f;
}

// async 16B global->LDS (gfx950). LDS dest = wave-uniform base + lane*16.
#define GLOAD_LDS16(g, l)                                                     \
  __builtin_amdgcn_global_load_lds(                                           \
      (const __attribute__((address_space(1))) void*)(g),                     \
      (__attribute__((address_space(3))) void*)(l), 16, 0, 0)

// ---------------------------------------------------------------- GN stats
__global__ __launch_bounds__(256) void gn_stats_k(const float* __restrict__ x,
                                                  float2* __restrict__ stats) {
  int bg = blockIdx.x;            // b*32+g
  int b = bg >> 5, g = bg & 31;
  int tid = threadIdx.x;
  int c = tid & 15, s0 = tid >> 4;
  const float* base = x + (long)b * SP * NC + g * 16 + c;
  float s = 0.f, ss = 0.f;
  for (int sp = s0; sp < SP; sp += 16) {
    float v = base[(long)sp * NC];
    s += v; ss += v * v;
  }
  for (int o = 32; o > 0; o >>= 1) { s += __shfl_xor(s, o); ss += __shfl_xor(ss, o); }
  __shared__ float rs[4], rss[4];
  int lane = tid & 63, wv = tid >> 6;
  if (lane == 0) { rs[wv] = s; rss[wv] = ss; }
  __syncthreads();
  if (tid == 0) {
    float S = rs[0] + rs[1] + rs[2] + rs[3];
    float SS = rss[0] + rss[1] + rss[2] + rss[3];
    float mean = S * (1.f / 16384.f);
    float var  = SS * (1.f / 16384.f) - mean * mean;
    stats[bg] = make_float2(mean, rsqrtf(var + EPSV));
  }
}

// ---------------------------------------------------------------- GN apply -> xn bf16
__global__ __launch_bounds__(256) void gn_apply_k(const float* __restrict__ x,
                                                  const float2* __restrict__ stats,
                                                  const float* __restrict__ gamma,
                                                  const float* __restrict__ beta,
                                                  unsigned short* __restrict__ xn) {
  long t = (long)blockIdx.x * 256 + threadIdx.x;
  long base = t * 8;
  int c = (int)(base & 511);
  int b = (int)(base >> 19);
  float2 st = stats[b * NG + (c >> 4)];
  f32x4 v0 = *reinterpret_cast<const f32x4*>(x + base);
  f32x4 v1 = *reinterpret_cast<const f32x4*>(x + base + 4);
  f32x4 g0 = *reinterpret_cast<const f32x4*>(gamma + c);
  f32x4 g1 = *reinterpret_cast<const f32x4*>(gamma + c + 4);
  f32x4 b0 = *reinterpret_cast<const f32x4*>(beta + c);
  f32x4 b1 = *reinterpret_cast<const f32x4*>(beta + c + 4);
  short8 o;
  #pragma unroll
  for (int q = 0; q < 4; ++q) {
    float sc = st.y * g0[q];
    o[q] = (short)f2bf(v0[q] * sc + (b0[q] - st.x * sc));
  }
  #pragma unroll
  for (int q = 0; q < 4; ++q) {
    float sc = st.y * g1[q];
    o[q + 4] = (short)f2bf(v1[q] * sc + (b1[q] - st.x * sc));
  }
  *reinterpret_cast<short8*>(xn + base) = o;
}

// ---------------------------------------------------------------- weight packing
__global__ __launch_bounds__(256) void pack_wqkv_k(const float* __restrict__ W,
                                                   const float* __restrict__ bq,
                                                   unsigned short* __restrict__ Wp,
                                                   float* __restrict__ bp) {
  int idx = blockIdx.x * 256 + threadIdx.x;     // 786432
  int n = idx >> 9, c = idx & 511;
  int e = n >> 9, a = n & 511;
  Wp[idx] = f2bf(W[((long)c * 512 + a) * 3 + e]);
  if (idx < 1536) {
    int e2 = idx >> 9, a2 = idx & 511;
    bp[idx] = bq[a2 * 3 + e2];
  }
}

__global__ __launch_bounds__(256) void pack_wout_k(const float* __restrict__ W,
                                                   unsigned short* __restrict__ Wp) {
  int idx = blockIdx.x * 256 + threadIdx.x;     // 262144
  int n = idx >> 9, c = idx & 511;
  Wp[idx] = f2bf(W[(long)c * 512 + n]);
}

// ---------------------------------------------------------------- V transpose
__global__ void transpose_v_k(const unsigned short* __restrict__ qkv,
                              unsigned short* __restrict__ vT) {
  __shared__ unsigned short t[32][33];
  int bs = blockIdx.x, bc = blockIdx.y, b = blockIdx.z;
  int tx = threadIdx.x, ty = threadIdx.y;     // 32 x 8
  #pragma unroll
  for (int k = 0; k < 4; ++k) {
    int s = bs * 32 + ty + k * 8, c = bc * 32 + tx;
    t[ty + k * 8][tx] = qkv[((long)b * SP + s) * 1536 + 1024 + c];
  }
  __syncthreads();
  #pragma unroll
  for (int k = 0; k < 4; ++k) {
    int c = bc * 32 + ty + k * 8, s = bs * 32 + tx;
    vT[((long)b * NC + c) * SP + s] = t[tx][ty + k * 8];
  }
}

// ---------------------------------------------------------------- softmax (bf16 in-place)
__global__ __launch_bounds__(256) void softmax_k(unsigned short* __restrict__ S) {
  long row = blockIdx.x;
  unsigned short* r = S + row * 1024;
  int tid = threadIdx.x, lane = tid & 63, wv = tid >> 6;
  short4v raw = *reinterpret_cast<const short4v*>(r + tid * 4);
  float v[4];
  #pragma unroll
  for (int q = 0; q < 4; ++q) v[q] = bf2f((unsigned short)raw[q]);
  float m = fmaxf(fmaxf(v[0], v[1]), fmaxf(v[2], v[3]));
  for (int o = 32; o > 0; o >>= 1) m = fmaxf(m, __shfl_xor(m, o));
  __shared__ float wm[4], ws[4];
  if (lane == 0) wm[wv] = m;
  __syncthreads();
  float rmax = fmaxf(fmaxf(wm[0], wm[1]), fmaxf(wm[2], wm[3]));
  float e[4]; float ssum = 0.f;
  #pragma unroll
  for (int q = 0; q < 4; ++q) { e[q] = __expf(v[q] - rmax); ssum += e[q]; }
  for (int o = 32; o > 0; o >>= 1) ssum += __shfl_xor(ssum, o);
  if (lane == 0) ws[wv] = ssum;
  __syncthreads();
  float inv = 1.f / (ws[0] + ws[1] + ws[2] + ws[3]);
  short4v pv;
  #pragma unroll
  for (int q = 0; q < 4; ++q) pv[q] = (short)f2bf(e[q] * inv);
  *reinterpret_cast<short4v*>(r + tid * 4) = pv;
}

// ---------------------------------------------------------------- pipelined TN GEMM
// C[m][n] = sum_k A[m][k]*B'[n][k], bf16. Tile 128x256, BK=32, 8 waves (2M x 4N),
// 4-deep LDS K-tile ring (96KB dynamic), staging 3 tiles ahead via global_load_lds,
// counted vmcnt (6 steady / 3,0 at tail - tile t+1 must be landed), raw s_barrier,
// setprio around MFMA.
// LDS swizzle: 16B slot s at (row r) stored at slot8' = ((r&1)*4+s) ^ ((r>>1)&7)
// within the 128B super-row r>>1 (involution; applied on stage-source AND read).
// EPI: 0 = bf16 out + fp32 bias, 2 = bf16 out * scale, 3 = fp32 out + bias + residual
template <int EPI>
__global__ __launch_bounds__(512, 2) void gemm8(
    const unsigned short* __restrict__ Ap, long strideA, int lda,
    const unsigned short* __restrict__ Bp, long strideB, int ldb,
    void* __restrict__ Op, long strideO, int ldo,
    const float* __restrict__ bias, const float* __restrict__ residual,
    int K, float scale) {
  constexpr int SLOT = 24576;              // A 8KB + B 16KB per K-tile
  extern __shared__ unsigned char smem[];  // 4 * 24576 = 98304
  const int tid = threadIdx.x;
  const int lane = tid & 63, wv = tid >> 6;
  const int wm2 = wv >> 2, wn4 = wv & 3;

  // bijective XCD swizzle (requires nwg % 8 == 0)
  const int nwg  = gridDim.x * gridDim.y;
  const int flat = blockIdx.y * gridDim.x + blockIdx.x;
  const int w    = (flat & 7) * (nwg >> 3) + (flat >> 3);
  const int bn = (w % gridDim.x) * 256;
  const int bm = (w / gridDim.x) * 128;
  const int z = blockIdx.z;
  const unsigned short* Ag = Ap + (long)z * strideA;
  const unsigned short* Bg = Bp + (long)z * strideB;

  // ---- stage-source offsets (inverse-swizzled global addresses; LDS dest linear)
  long offA;
  { int sid = tid, sr = sid >> 3, sl = (sid & 7) ^ (sr & 7);
    offA = (long)(bm + sr * 2 + (sl >> 2)) * lda + (sl & 3) * 8; }
  long offB0, offB1;
  { int sid = tid, sr = sid >> 3, sl = (sid & 7) ^ (sr & 7);
    offB0 = (long)(bn + sr * 2 + (sl >> 2)) * ldb + (sl & 3) * 8;
    sid = 512 + tid; sr = sid >> 3; sl = (sid & 7) ^ (sr & 7);
    offB1 = (long)(bn + sr * 2 + (sl >> 2)) * ldb + (sl & 3) * 8; }
  const int ldsA_off  = wv * 1024;
  const int ldsB0_off = 8192 + wv * 1024;
  const int ldsB1_off = 16384 + wv * 1024;

  // ---- swizzled LDS read offsets (A frags i=0..3, B frags j=0..3)
  int aoff[4], boff[4];
  #pragma unroll
  for (int i = 0; i < 4; ++i) {
    int r = wm2 * 64 + i * 16 + (lane & 15);
    int sr = r >> 1, sl = ((r & 1) * 4 + (lane >> 4)) ^ (sr & 7);
    aoff[i] = sr * 128 + sl * 16;
  }
  #pragma unroll
  for (int j = 0; j < 4; ++j) {
    int r = wn4 * 64 + j * 16 + (lane & 15);
    int sr = r >> 1, sl = ((r & 1) * 4 + (lane >> 4)) ^ (sr & 7);
    boff[j] = 8192 + sr * 128 + sl * 16;
  }

  const int NT = K >> 5;
  // ---- prologue: stage K-tiles 0,1,2 (9 loads); wait tile0 (leave 6 in flight)
  #pragma unroll
  for (int t = 0; t < 3; ++t) {
    int sb = t * SLOT, kt = t * 32;
    GLOAD_LDS16(Ag + offA + kt,  smem + sb + ldsA_off);
    GLOAD_LDS16(Bg + offB0 + kt, smem + sb + ldsB0_off);
    GLOAD_LDS16(Bg + offB1 + kt, smem + sb + ldsB1_off);
  }
  asm volatile("s_waitcnt vmcnt(6)" ::: "memory");
  __builtin_amdgcn_s_barrier();

  f32x4 acc[4][4] = {};
  for (int t = 0; t < NT; ++t) {
    const unsigned char* sa = smem + (t & 3) * SLOT;
    short8 av[4], bv[4];
    #pragma unroll
    for (int i = 0; i < 4; ++i)
      av[i] = *reinterpret_cast<const short8*>(sa + aoff[i]);
    #pragma unroll
    for (int j = 0; j < 4; ++j)
      bv[j] = *reinterpret_cast<const short8*>(sa + boff[j]);
    if (t + 3 < NT) {   // stage tile t+3 into slot (t+3)&3 (= dead tile t-1's slot)
      int sb = ((t + 3) & 3) * SLOT, kt = (t + 3) * 32;
      GLOAD_LDS16(Ag + offA + kt,  smem + sb + ldsA_off);
      GLOAD_LDS16(Bg + offB0 + kt, smem + sb + ldsB0_off);
      GLOAD_LDS16(Bg + offB1 + kt, smem + sb + ldsB1_off);
    }
    __builtin_amdgcn_s_barrier();
    asm volatile("s_waitcnt lgkmcnt(0)" ::: "memory");
    __builtin_amdgcn_sched_barrier(0);
    __builtin_amdgcn_s_setprio(1);
    #pragma unroll
    for (int i = 0; i < 4; ++i)
      #pragma unroll
      for (int j = 0; j < 4; ++j)
        acc[i][j] = __builtin_amdgcn_mfma_f32_16x16x32_bf16(
            __builtin_bit_cast(bf16x8v, av[i]),
            __builtin_bit_cast(bf16x8v, bv[j]), acc[i][j], 0, 0, 0);
    __builtin_amdgcn_s_setprio(0);
    __builtin_amdgcn_sched_barrier(0);
    // need tile t+1 fully landed before next iteration reads it.
    // while staging: 6 newer ops in flight (tiles t+2,t+3) -> vmcnt(6).
    // tail (stage stopped): newer-than-t+1 ops shrink -> vmcnt(3), then (0).
    if (t + 3 < NT) {
      asm volatile("s_waitcnt vmcnt(6)" ::: "memory");
    } else if (t + 2 < NT) {
      asm volatile("s_waitcnt vmcnt(3)" ::: "memory");
    } else {
      asm volatile("s_waitcnt vmcnt(0)" ::: "memory");
    }
    __builtin_amdgcn_s_barrier();
  }

  // ---- epilogue  (C/D map: col=lane&15, row=(lane>>4)*4+reg  [m89])
  const int colb = bn + wn4 * 64 + (lane & 15);
  const int rowb = bm + wm2 * 64 + (lane >> 4) * 4;
  #pragma unroll
  for (int i = 0; i < 4; ++i) {
    #pragma unroll
    for (int r = 0; r < 4; ++r) {
      int rowg = rowb + i * 16 + r;
      #pragma unroll
      for (int j = 0; j < 4; ++j) {
        int colg = colb + j * 16;
        float v = acc[i][j][r];
        if (EPI == 0) {
          v += bias[colg];
          ((unsigned short*)Op)[(long)z * strideO + (long)rowg * ldo + colg] = f2bf(v);
        } else if (EPI == 2) {
          ((unsigned short*)Op)[(long)z * strideO + (long)rowg * ldo + colg] = f2bf(v * scale);
        } else {
          v += bias[colg] + residual[(long)rowg * ldo + colg];
          ((float*)Op)[(long)rowg * ldo + colg] = v;
        }
      }
    }
  }
}

// ---------------------------------------------------------------- launch
extern "C" void kernel_launch(void* const* d_in, const int* in_sizes, int n_in,
                              void* d_out, int out_size, void* d_ws, size_t ws_size,
                              hipStream_t stream) {
  const float* x     = (const float*)d_in[0];
  const float* gamma = (const float*)d_in[1];
  const float* beta  = (const float*)d_in[2];
  const float* Wqkv  = (const float*)d_in[3];
  const float* bqkv  = (const float*)d_in[4];
  const float* Wout  = (const float*)d_in[5];
  const float* bout  = (const float*)d_in[6];
  float* out = (float*)d_out;

  char* ws = (char*)d_ws;
  float2*         stats = (float2*)(ws + 0);                    //   4 KB
  unsigned short* wqkvP = (unsigned short*)(ws + 4096);         // 1.5 MB
  float*          bqP   = (float*)(ws + 1576960);               //   6 KB
  unsigned short* woutT = (unsigned short*)(ws + 1583104);      // 0.5 MB
  unsigned short* qkv   = (unsigned short*)(ws + 2107392);      //  48 MB  [16384][1536] bf16
  unsigned short* vT    = (unsigned short*)(ws + 52439040);     //  16 MB  [16][512][1024] bf16
  unsigned short* Sbuf  = (unsigned short*)(ws + 69216256);     //  32 MB  [16][1024][1024] bf16 (P in-place)
  unsigned short* attn  = (unsigned short*)(ws + 136325120);    //  16 MB  [16384][512] bf16
  unsigned short* xn    = (unsigned short*)(ws + 153102336);    //  16 MB  [16384][512] bf16

  // opt in to 96KB dynamic LDS (host-side, not a stream op - capture-safe)
  (void)hipFuncSetAttribute((const void*)gemm8<0>,
        hipFuncAttributeMaxDynamicSharedMemorySize, 98304);
  (void)hipFuncSetAttribute((const void*)gemm8<2>,
        hipFuncAttributeMaxDynamicSharedMemorySize, 98304);
  (void)hipFuncSetAttribute((const void*)gemm8<3>,
        hipFuncAttributeMaxDynamicSharedMemorySize, 98304);

  gn_stats_k<<<512, 256, 0, stream>>>(x, stats);
  gn_apply_k<<<4096, 256, 0, stream>>>(x, stats, gamma, beta, xn);
  pack_wqkv_k<<<3072, 256, 0, stream>>>(Wqkv, bqkv, wqkvP, bqP);
  pack_wout_k<<<1024, 256, 0, stream>>>(Wout, woutT);

  // QKV projection: xn [16384,512] x wqkvP [1536,512]^T -> qkv bf16 [16384][1536]
  gemm8<0><<<dim3(6, 128, 1), 512, 98304, stream>>>(
      xn, 0L, NC, wqkvP, 0L, NC, qkv, 0L, 1536,
      bqP, nullptr, NC, 1.f);

  transpose_v_k<<<dim3(32, 16, 16), dim3(32, 8), 0, stream>>>(qkv, vT);

  // S = Q K^T * scale (bf16 out, per batch): A=q (cols 0..511), B'=k (cols 512..1023)
  gemm8<2><<<dim3(4, 8, 16), 512, 98304, stream>>>(
      qkv, (long)SP * 1536, 1536, qkv + 512, (long)SP * 1536, 1536,
      Sbuf, (long)SP * SP, SP, nullptr, nullptr, NC, SCALE);

  softmax_k<<<MTOT, 256, 0, stream>>>(Sbuf);

  // attn_out = P V  (per batch): A=P bf16 [1024][1024], B'=vT [512][1024]
  gemm8<2><<<dim3(2, 8, 16), 512, 98304, stream>>>(
      Sbuf, (long)SP * SP, SP, vT, (long)NC * SP, SP,
      attn, (long)SP * NC, NC, nullptr, nullptr, SP, 1.f);

  // out = attn_out W_out + b_out + inputs
  gemm8<3><<<dim3(2, 128, 1), 512, 98304, stream>>>(
      attn, 0L, NC, woutT, 0L, NC, out, 0L, NC,
      bout, x, NC, 1.f);
}